// Round 2
// baseline (152.983 us; speedup 1.0000x reference)
//
#include <hip/hip_runtime.h>

#define NN 8192      // nodes
#define NE 262144    // edges
#define DIM 128

typedef float f32x4 __attribute__((ext_vector_type(4)));

// ---------------- helpers ----------------
__device__ __forceinline__ float4 f4fma(float s, float4 w, float4 acc) {
    acc.x = fmaf(s, w.x, acc.x);
    acc.y = fmaf(s, w.y, acc.y);
    acc.z = fmaf(s, w.z, acc.z);
    acc.w = fmaf(s, w.w, acc.w);
    return acc;
}

// ---------------- CSR build ----------------
__global__ void zero_kernel(int* __restrict__ p, int n) {
    int i = blockIdx.x * blockDim.x + threadIdx.x;
    if (i < n) p[i] = 0;
}

__global__ void hist_kernel(const int* __restrict__ dst, int* __restrict__ cnt) {
    int e = blockIdx.x * blockDim.x + threadIdx.x;
    if (e < NE) atomicAdd(&cnt[dst[e]], 1);
}

__global__ __launch_bounds__(1024) void scan_kernel(const int* __restrict__ cnt,
                                                    int* __restrict__ offs,
                                                    float* __restrict__ dinv) {
    __shared__ int part[1024];
    int t = threadIdx.x;
    int base = t * 8;
    int v[8];
    int s = 0;
#pragma unroll
    for (int i = 0; i < 8; ++i) { v[i] = cnt[base + i]; s += v[i]; }
    part[t] = s;
    __syncthreads();
    for (int off = 1; off < 1024; off <<= 1) {
        int x = 0;
        if (t >= off) x = part[t - off];
        __syncthreads();
        part[t] += x;
        __syncthreads();
    }
    int run = (t > 0) ? part[t - 1] : 0;
#pragma unroll
    for (int i = 0; i < 8; ++i) {
        offs[base + i] = run;
        run += v[i];
        dinv[base + i] = rsqrtf((float)(v[i] + 1));  // deg = indegree + self loop
    }
    if (t == 1023) offs[NN] = run;
}

__global__ void scatter_kernel(const int* __restrict__ src, const int* __restrict__ dst,
                               const int* __restrict__ offs, int* __restrict__ cursor,
                               int* __restrict__ srcs) {
    int e = blockIdx.x * blockDim.x + threadIdx.x;
    if (e < NE) {
        int d = dst[e];
        int p = atomicAdd(&cursor[d], 1);
        srcs[offs[d] + p] = src[e];
    }
}

// ---------------- u = W_out @ w_i, v = W_out @ w_j, beta = {b_out.w_i + b_edge, b_out.w_j} ----------------
__global__ __launch_bounds__(128) void uv_kernel(const float* __restrict__ Wout,
                                                 const float* __restrict__ bout,
                                                 const float* __restrict__ we,
                                                 const float* __restrict__ bedge,
                                                 float* __restrict__ u, float* __restrict__ v,
                                                 float* __restrict__ beta) {
    int k = threadIdx.x;
    float su = 0.f, sv = 0.f;
    for (int j = 0; j < DIM; ++j) {
        float w = Wout[k * DIM + j];
        su = fmaf(w, we[j], su);
        sv = fmaf(w, we[DIM + j], sv);
    }
    u[k] = su;
    v[k] = sv;
    __shared__ float red[128];
    red[k] = bout[k] * we[k];
    __syncthreads();
    for (int off = 64; off >= 1; off >>= 1) {
        if (k < off) red[k] += red[k + off];
        __syncthreads();
    }
    float b0 = red[0];
    __syncthreads();
    red[k] = bout[k] * we[DIM + k];
    __syncthreads();
    for (int off = 64; off >= 1; off >>= 1) {
        if (k < off) red[k] += red[k + off];
        __syncthreads();
    }
    if (k == 0) {
        beta[0] = b0 + bedge[0];
        beta[1] = red[0];
    }
}

// ---------------- GEMM: G[r][c] = (X @ W)[r][c] * dinv[r]   (M=8192, K=N=128) ----------------
__global__ __launch_bounds__(256) void gemm_scaled(const float* __restrict__ X,
                                                   const float* __restrict__ W,
                                                   const float* __restrict__ dinv,
                                                   float* __restrict__ G) {
    __shared__ float4 Wl[128 * 32];  // [k][c4]  64KB
    __shared__ float4 Xl[32 * 32];   // [r][k4]  16KB
    int tid = threadIdx.x;
    int rbase = blockIdx.x * 32;

    const float4* W4 = (const float4*)W;
#pragma unroll
    for (int i = 0; i < 16; ++i) Wl[i * 256 + tid] = W4[i * 256 + tid];
    const float4* X4 = (const float4*)(X + rbase * DIM);
#pragma unroll
    for (int i = 0; i < 4; ++i) Xl[i * 256 + tid] = X4[i * 256 + tid];
    __syncthreads();

    int tx = tid & 31;  // col group: cols tx*4..tx*4+3
    int ty = tid >> 5;  // row group: rows ty*4..ty*4+3
    float4 acc[4];
#pragma unroll
    for (int i = 0; i < 4; ++i) acc[i] = make_float4(0.f, 0.f, 0.f, 0.f);

    for (int k4 = 0; k4 < 32; ++k4) {
        float4 w0 = Wl[(k4 * 4 + 0) * 32 + tx];
        float4 w1 = Wl[(k4 * 4 + 1) * 32 + tx];
        float4 w2 = Wl[(k4 * 4 + 2) * 32 + tx];
        float4 w3 = Wl[(k4 * 4 + 3) * 32 + tx];
#pragma unroll
        for (int i = 0; i < 4; ++i) {
            float4 xv = Xl[(ty * 4 + i) * 32 + k4];
            acc[i] = f4fma(xv.x, w0, acc[i]);
            acc[i] = f4fma(xv.y, w1, acc[i]);
            acc[i] = f4fma(xv.z, w2, acc[i]);
            acc[i] = f4fma(xv.w, w3, acc[i]);
        }
    }

    float4* G4 = (float4*)G;
#pragma unroll
    for (int i = 0; i < 4; ++i) {
        int r = rbase + ty * 4 + i;
        float di = dinv[r];
        float4 o = acc[i];
        o.x *= di; o.y *= di; o.z *= di; o.w *= di;
        G4[r * 32 + tx] = o;
    }
}

// ---------------- aggregation: one wave per node, lane holds 2 of 128 features ----------------
template <int FINAL>
__global__ __launch_bounds__(256) void agg_kernel(const float* __restrict__ G,
                                                  const int* __restrict__ offs,
                                                  const int* __restrict__ srcs,
                                                  const float* __restrict__ dinv,
                                                  const float* __restrict__ bias,
                                                  float* __restrict__ Hout,
                                                  const float* __restrict__ u,
                                                  const float* __restrict__ v,
                                                  const float* __restrict__ beta,
                                                  float* __restrict__ a,
                                                  float* __restrict__ c) {
    int node = blockIdx.x * 4 + (threadIdx.x >> 6);
    int lane = threadIdx.x & 63;
    if (node >= NN) return;
    const float2* G2 = (const float2*)G;
    float2 acc = G2[node * 64 + lane];  // self-loop term
    int e0 = offs[node], e1 = offs[node + 1];
    for (int e = e0; e < e1; ++e) {
        int s = srcs[e];
        float2 t = G2[s * 64 + lane];
        acc.x += t.x;
        acc.y += t.y;
    }
    float di = dinv[node];
    const float2* B2 = (const float2*)bias;
    float2 b = B2[lane];
    float h0 = fmaxf(fmaf(acc.x, di, b.x), 0.f);
    float h1 = fmaxf(fmaf(acc.y, di, b.y), 0.f);
    if (FINAL == 0) {
        float2 o;
        o.x = h0;
        o.y = h1;
        ((float2*)Hout)[node * 64 + lane] = o;
    } else {
        const float2* U2 = (const float2*)u;
        const float2* V2 = (const float2*)v;
        float2 uu = U2[lane], vv = V2[lane];
        float pu = h0 * uu.x + h1 * uu.y;
        float pv = h0 * vv.x + h1 * vv.y;
#pragma unroll
        for (int off = 32; off >= 1; off >>= 1) {
            pu += __shfl_xor(pu, off);
            pv += __shfl_xor(pv, off);
        }
        if (lane == 0) {
            a[node] = pu + beta[0];
            c[node] = pv + beta[1];
        }
    }
}

// ---------------- out[i][j] = a[i] + c[j] ----------------
__global__ __launch_bounds__(256) void out_kernel(const float* __restrict__ a,
                                                  const float* __restrict__ c,
                                                  float* __restrict__ out) {
    int idx = blockIdx.x * 256 + threadIdx.x;  // one float4 per thread
    int i = idx >> 11;                         // row (2048 float4 per row)
    int j4 = idx & 2047;
    float av = a[i];
    float4 cv = ((const float4*)c)[j4];
    f32x4 r;
    r.x = cv.x + av;
    r.y = cv.y + av;
    r.z = cv.z + av;
    r.w = cv.w + av;
    __builtin_nontemporal_store(r, ((f32x4*)out) + idx);
}

extern "C" void kernel_launch(void* const* d_in, const int* in_sizes, int n_in,
                              void* d_out, int out_size, void* d_ws, size_t ws_size,
                              hipStream_t stream) {
    const float* x    = (const float*)d_in[0];
    const int*   ei   = (const int*)d_in[1];
    const float* W1   = (const float*)d_in[2];
    const float* b1   = (const float*)d_in[3];
    const float* W2   = (const float*)d_in[4];
    const float* b2   = (const float*)d_in[5];
    const float* Wout = (const float*)d_in[6];
    const float* bout = (const float*)d_in[7];
    const float* We   = (const float*)d_in[8];
    const float* bedge= (const float*)d_in[9];
    const int* src = ei;
    const int* dst = ei + NE;

    // workspace layout (all offsets multiples of 16B)
    int* cnt    = (int*)d_ws;            // 8192
    int* cursor = cnt + NN;              // 8192
    int* offs   = cursor + NN;           // 8193 (padded to 8704)
    int* srcs   = offs + 8704;           // 262144
    float* dinv = (float*)(srcs + NE);   // 8192
    float* u    = dinv + NN;             // 128
    float* v    = u + DIM;               // 128
    float* beta = v + DIM;               // 2 (padded to 64)
    float* g    = beta + 64;             // 8192*128
    float* h1b  = g + NN * DIM;          // 8192*128
    float* av   = h1b + NN * DIM;        // 8192
    float* cv   = av + NN;               // 8192

    float* out = (float*)d_out;

    zero_kernel<<<(2 * NN + 255) / 256, 256, 0, stream>>>(cnt, 2 * NN);
    hist_kernel<<<NE / 256, 256, 0, stream>>>(dst, cnt);
    scan_kernel<<<1, 1024, 0, stream>>>(cnt, offs, dinv);
    scatter_kernel<<<NE / 256, 256, 0, stream>>>(src, dst, offs, cursor, srcs);
    uv_kernel<<<1, 128, 0, stream>>>(Wout, bout, We, bedge, u, v, beta);

    gemm_scaled<<<NN / 32, 256, 0, stream>>>(x, W1, dinv, g);
    agg_kernel<0><<<NN / 4, 256, 0, stream>>>(g, offs, srcs, dinv, b1, h1b,
                                              nullptr, nullptr, nullptr, nullptr, nullptr);
    gemm_scaled<<<NN / 32, 256, 0, stream>>>(h1b, W2, dinv, g);
    agg_kernel<1><<<NN / 4, 256, 0, stream>>>(g, offs, srcs, dinv, b2, nullptr,
                                              u, v, beta, av, cv);
    out_kernel<<<(NN / 1) * (NN / 4) / 256, 256, 0, stream>>>(av, cv, out);
}